// Round 1
// baseline (85.078 us; speedup 1.0000x reference)
//
#include <hip/hip_runtime.h>

#define B_SZ 8192
#define L_SZ 128
#define P_PAIRS 4096
#define NBLK_G 64                  // gram blocks; entries = rows 0..1 of gram
#define MARGIN 64.0f
#define GRID_N 384

// 4-byte-word offsets into ws (layout unchanged)
#define CNT_OFF   0                // int[64]     per-gram-block candidate count
#define CB_OFF    64               // u64[64*4]   per-block 256-bit candmask (512 words, byte 256, 8-aligned)
#define POS_OFF   576              // float[512]  per-wave pos-hinge partials
#define QUANT_OFF 1088             // float[128]  per-block quant partials
#define BITS_OFF  1216             // float[64*128] bit colsum partials
#define VSUM_OFF  9408             // float[64]   per-block full candidate v^2 sum
#define GRAM_OFF  9472             // float[16384] gram rows 0..1

// Arrival ticket. Lives in the code object's .data (NOT in d_ws), so the harness's
// workspace poison can't touch it. Loader zero-inits; the finale block resets it
// to 0 at the end of every dispatch, so graph replays always start from 0.
__device__ int g_ticket = 0;

// ---- Single fused kernel: all roles + last-arriving block runs the finale ----
__global__ __launch_bounds__(256) void k_fused(const float* __restrict__ bin,
                                               const float* __restrict__ cont,
                                               const int* __restrict__ pos,
                                               void* __restrict__ wsv,
                                               float* __restrict__ out) {
    float* ws_f = (float*)wsv;
    int* ws_i = (int*)wsv;
    const int bid = blockIdx.x, tid = threadIdx.x;
    const int lane = tid & 63, wv = tid >> 6;

    if (bid < NBLK_G) {                               // ---- gram + cand/count/vsum ----
        __shared__ float rowi[L_SZ];
        __shared__ unsigned char flag[256];
        __shared__ float rsum[4];
        __shared__ int rcnt[4];
        const int b = bid;
        const int i = b >> 5;                          // row 0 or 1
        const int jbase = (b & 31) * 256;
        flag[tid] = 0;
        if (tid < L_SZ) rowi[tid] = bin[i * L_SZ + tid];
        __syncthreads();
        const int2* pp = (const int2*)pos;
#pragma unroll
        for (int r = 0; r < P_PAIRS / 256; ++r) {      // mark positives hitting my range
            int2 qd = pp[r * 256 + tid];
            if (qd.x == i) { int dj = qd.y - jbase; if ((unsigned)dj < 256u) flag[dj] = 1; }
            if (qd.y == i) { int dj = qd.x - jbase; if ((unsigned)dj < 256u) flag[dj] = 1; }
        }
        __syncthreads();
        const int j = jbase + tid;
        const float4* rj = (const float4*)(bin + (long)j * L_SZ);
        const float4* ri4 = (const float4*)rowi;
        float s = 0.f;
#pragma unroll
        for (int k = 0; k < 32; ++k) {
            float4 a = ri4[k], c = rj[k];
            s += a.x * c.x + a.y * c.y + a.z * c.z + a.w * c.w;
        }
        ws_f[GRAM_OFF + b * 256 + tid] = s;
        const bool cand = (j != i) && !flag[tid];
        unsigned long long bm = __ballot(cand);
        if (lane == 0)
            ((unsigned long long*)(ws_i + CB_OFF))[b * 4 + wv] = bm;
        float v = cand ? fmaxf(s + MARGIN, 0.f) : 0.f;
        v = v * v;
        int cnt = cand ? 1 : 0;
#pragma unroll
        for (int o = 32; o; o >>= 1) { v += __shfl_down(v, o); cnt += __shfl_down(cnt, o); }
        if (lane == 0) { rsum[wv] = v; rcnt[wv] = cnt; }
        __syncthreads();
        if (tid == 0) {
            ws_f[VSUM_OFF + b] = rsum[0] + rsum[1] + rsum[2] + rsum[3];
            ws_i[CNT_OFF + b] = rcnt[0] + rcnt[1] + rcnt[2] + rcnt[3];
        }
    } else if (bid < 192) {                           // ---- pos pairs: 4 pairs/wave-step ----
        const int w = (bid - 64) * 4 + wv;            // wave id [0,512), 8 pairs each
        const int sub = lane >> 4, sl = lane & 15;
        float contrib = 0.f;
#pragma unroll
        for (int st = 0; st < 2; ++st) {
            int p = w * 8 + st * 4 + sub;
            int q = pos[2 * p], d = pos[2 * p + 1];
            const float4* rq = (const float4*)(bin + (long)q * L_SZ);
            const float4* rd = (const float4*)(bin + (long)d * L_SZ);
            float4 a0 = rq[sl], a1 = rq[sl + 16];
            float4 b0 = rd[sl], b1 = rd[sl + 16];
            float s = a0.x * b0.x + a0.y * b0.y + a0.z * b0.z + a0.w * b0.w
                    + a1.x * b1.x + a1.y * b1.y + a1.z * b1.z + a1.w * b1.w;
            s += __shfl_down(s, 8); s += __shfl_down(s, 4);
            s += __shfl_down(s, 2); s += __shfl_down(s, 1);
            if (sl == 0) { float m = fmaxf(MARGIN - s, 0.f); contrib += m * m; }
        }
        contrib += __shfl_down(contrib, 16);          // lanes 0,16,32,48 -> lane 0
        contrib += __shfl_down(contrib, 32);
        if (lane == 0) ws_f[POS_OFF + w] = contrib;
    } else if (bid < 320) {                           // ---- quant ----
        int idx = (bid - 192) * 256 + tid;
        const float4* c4 = (const float4*)cont;
        float s = 0.f;
#pragma unroll
        for (int k = 0; k < 8; ++k) {
            float4 v = c4[idx + k * 32768];
            s += fabsf(fabsf(v.x) - 1.f) + fabsf(fabsf(v.y) - 1.f) +
                 fabsf(fabsf(v.z) - 1.f) + fabsf(fabsf(v.w) - 1.f);
        }
#pragma unroll
        for (int o = 32; o; o >>= 1) s += __shfl_down(s, o);
        __shared__ float sw[4];
        if (lane == 0) sw[wv] = s;
        __syncthreads();
        if (tid == 0) ws_f[QUANT_OFF + (bid - 192)] = sw[0] + sw[1] + sw[2] + sw[3];
    } else {                                          // ---- bit colsums ----
        int b = bid - 320;                            // 64 blocks x 128 rows
        int col = tid & 127, half = tid >> 7;
        long base = (long)b * 128;
        float s = 0.f;
        for (int r = half; r < 128; r += 2)
            s += bin[(base + r) * L_SZ + col];
        __shared__ float sh[256];
        sh[tid] = s;
        __syncthreads();
        if (tid < 128) ws_f[BITS_OFF + b * 128 + tid] = sh[tid] + sh[tid + 128];
    }

    // ---- arrival: last-arriving block runs the finale (no block ever waits) ----
    __syncthreads();                 // all role stores drained (barrier implies vmcnt drain)
    __shared__ int s_last;
    if (tid == 0) {
        __threadfence();             // agent-scope release: write back our ws lines
        s_last = (atomicAdd(&g_ticket, 1) == GRID_N - 1) ? 1 : 0;
    }
    __syncthreads();
    if (!s_last) return;
    __threadfence();                 // agent-scope acquire: invalidate stale L1/L2 lines

    // ---- finale: verbatim k_fin body ----
    {
        const int t = tid;
        __shared__ int meta[2];                           // cstar, rem
        __shared__ int wtot[4], woff_s[4];
        __shared__ float fsh[256];
        __shared__ float fred[4];

        if (wv == 0) {                                    // scan 64 block counts
            int c = ws_i[CNT_OFF + lane];
            int x = c;
#pragma unroll
            for (int o = 1; o < 64; o <<= 1) {
                int y = __shfl_up(x, o);
                if (lane >= o) x += y;
            }
            if ((x - c) < P_PAIRS && x >= P_PAIRS) {      // unique crossing lane
                meta[0] = lane; meta[1] = P_PAIRS - (x - c);
            }
        }
        __syncthreads();
        const int cstar = meta[0], rem = meta[1];

        // rank within cutoff block via ballot scan over 256 entries
        unsigned long long cw =
            ((const unsigned long long*)(ws_i + CB_OFF))[cstar * 4 + wv];
        const bool cand = (cw >> lane) & 1ull;
        unsigned long long bm = __ballot(cand);
        int rw = __popcll(bm & ((1ull << lane) - 1ull));
        if (lane == 63) wtot[wv] = __popcll(bm);
        __syncthreads();
        if (t == 0) { int s = 0; for (int w = 0; w < 4; ++w) { woff_s[w] = s; s += wtot[w]; } }
        __syncthreads();
        const int rank = woff_s[wv] + rw;

        const float inv2p = 1.0f / (float)(2 * P_PAIRS);
        float val = 0.f;
        if (cand && rank < rem) {
            float g = ws_f[GRAM_OFF + cstar * 256 + t];
            float u = fmaxf(g + MARGIN, 0.f);
            val += u * u * inv2p;
        }
        if (t < 64 && t < cstar) val += ws_f[VSUM_OFF + t] * inv2p;
        val += (ws_f[POS_OFF + t] + ws_f[POS_OFF + 256 + t]) * inv2p;
        if (t < 128) val += ws_f[QUANT_OFF + t] * (0.5f / (float)(B_SZ * L_SZ));

        {   // bit-balance: 64 partials per col
            int col = t & 127, g = t >> 7;
            float s2 = 0.f;
            for (int b = g * 32; b < g * 32 + 32; ++b) s2 += ws_f[BITS_OFF + b * 128 + col];
            fsh[t] = s2;
        }
        __syncthreads();
        if (t < 128) {
            float cs = fsh[t] + fsh[t + 128];
            float m = cs * (1.0f / (float)B_SZ);
            val += 0.1f * m * m;
        }
        __syncthreads();
#pragma unroll
        for (int o = 32; o; o >>= 1) val += __shfl_down(val, o);
        if (lane == 0) fred[wv] = val;
        __syncthreads();
        if (t == 0) {
            out[0] = fred[0] + fred[1] + fred[2] + fred[3];
            // reset ticket for the next graph replay (published by dispatch-end release)
            __hip_atomic_store(&g_ticket, 0, __ATOMIC_RELAXED, __HIP_MEMORY_SCOPE_AGENT);
        }
    }
}

extern "C" void kernel_launch(void* const* d_in, const int* in_sizes, int n_in,
                              void* d_out, int out_size, void* d_ws, size_t ws_size,
                              hipStream_t stream) {
    const float* bin = (const float*)d_in[0];
    const float* cont = (const float*)d_in[1];
    const int* pos = (const int*)d_in[2];
    float* out = (float*)d_out;

    k_fused<<<GRID_N, 256, 0, stream>>>(bin, cont, pos, d_ws, out);
}

// Round 2
// 79.215 us; speedup vs baseline: 1.0740x; 1.0740x over previous
//
#include <hip/hip_runtime.h>

#define B_SZ 8192
#define L_SZ 128
#define P_PAIRS 4096
#define NBLK_G 32                  // gram blocks: row 0 only (cutoff provably lands in row 0)
#define MARGIN 64.0f

// 4-byte-word offsets into ws (layout unchanged from 79.3µs baseline; slots beyond
// 32 gram blocks are simply unused now)
#define CNT_OFF   0                // int[64]     per-gram-block candidate count (32 used)
#define CB_OFF    64               // u64[64*4]   per-block 256-bit candmask (32*4 used)
#define POS_OFF   576              // float[512]  per-wave pos-hinge partials
#define QUANT_OFF 1088             // float[128]  per-block quant partials
#define BITS_OFF  1216             // float[64*128] bit colsum partials
#define VSUM_OFF  9408             // float[64]   per-block full candidate v^2 sum (32 used)
#define GRAM_OFF  9472             // float[16384] gram row 0 (8192 used)

// ---- Kernel A: all parallel work, role by block range --------------------
// grid = 352: [0,32) gram row 0 | [32,160) pos pairs | [160,288) quant | [288,352) colsums
__global__ __launch_bounds__(256) void k_all(const float* __restrict__ bin,
                                             const float* __restrict__ cont,
                                             const int* __restrict__ pos,
                                             void* __restrict__ wsv) {
    float* ws_f = (float*)wsv;
    int* ws_i = (int*)wsv;
    const int bid = blockIdx.x, tid = threadIdx.x;
    const int lane = tid & 63, wv = tid >> 6;

    if (bid < NBLK_G) {                               // ---- gram row 0 + cand/count/vsum ----
        __shared__ float rowi[L_SZ];
        __shared__ unsigned char flag[256];
        __shared__ float rsum[4];
        __shared__ int rcnt[4];
        const int b = bid;
        const int jbase = b * 256;                     // columns [jbase, jbase+256) of row 0
        flag[tid] = 0;
        if (tid < L_SZ) rowi[tid] = bin[tid];          // row 0
        __syncthreads();
        const int2* pp = (const int2*)pos;
#pragma unroll
        for (int r = 0; r < P_PAIRS / 256; ++r) {      // mark positives hitting row 0, my cols
            int2 qd = pp[r * 256 + tid];
            if (qd.x == 0) { int dj = qd.y - jbase; if ((unsigned)dj < 256u) flag[dj] = 1; }
            if (qd.y == 0) { int dj = qd.x - jbase; if ((unsigned)dj < 256u) flag[dj] = 1; }
        }
        __syncthreads();
        const int j = jbase + tid;
        const float4* rj = (const float4*)(bin + (long)j * L_SZ);
        const float4* ri4 = (const float4*)rowi;
        float s = 0.f;
#pragma unroll
        for (int k = 0; k < 32; ++k) {
            float4 a = ri4[k], c = rj[k];
            s += a.x * c.x + a.y * c.y + a.z * c.z + a.w * c.w;
        }
        ws_f[GRAM_OFF + b * 256 + tid] = s;
        const bool cand = (j != 0) && !flag[tid];      // diagonal is (0,0) only
        unsigned long long bm = __ballot(cand);
        if (lane == 0)
            ((unsigned long long*)(ws_i + CB_OFF))[b * 4 + wv] = bm;
        float v = cand ? fmaxf(s + MARGIN, 0.f) : 0.f;
        v = v * v;
        int cnt = cand ? 1 : 0;
#pragma unroll
        for (int o = 32; o; o >>= 1) { v += __shfl_down(v, o); cnt += __shfl_down(cnt, o); }
        if (lane == 0) { rsum[wv] = v; rcnt[wv] = cnt; }
        __syncthreads();
        if (tid == 0) {
            ws_f[VSUM_OFF + b] = rsum[0] + rsum[1] + rsum[2] + rsum[3];
            ws_i[CNT_OFF + b] = rcnt[0] + rcnt[1] + rcnt[2] + rcnt[3];
        }
    } else if (bid < 160) {                           // ---- pos pairs: 4 pairs/wave-step ----
        const int w = (bid - 32) * 4 + wv;            // wave id [0,512), 8 pairs each
        const int sub = lane >> 4, sl = lane & 15;
        float contrib = 0.f;
#pragma unroll
        for (int st = 0; st < 2; ++st) {
            int p = w * 8 + st * 4 + sub;
            int q = pos[2 * p], d = pos[2 * p + 1];
            const float4* rq = (const float4*)(bin + (long)q * L_SZ);
            const float4* rd = (const float4*)(bin + (long)d * L_SZ);
            float4 a0 = rq[sl], a1 = rq[sl + 16];
            float4 b0 = rd[sl], b1 = rd[sl + 16];
            float s = a0.x * b0.x + a0.y * b0.y + a0.z * b0.z + a0.w * b0.w
                    + a1.x * b1.x + a1.y * b1.y + a1.z * b1.z + a1.w * b1.w;
            s += __shfl_down(s, 8); s += __shfl_down(s, 4);
            s += __shfl_down(s, 2); s += __shfl_down(s, 1);
            if (sl == 0) { float m = fmaxf(MARGIN - s, 0.f); contrib += m * m; }
        }
        contrib += __shfl_down(contrib, 16);          // lanes 0,16,32,48 -> lane 0
        contrib += __shfl_down(contrib, 32);
        if (lane == 0) ws_f[POS_OFF + w] = contrib;
    } else if (bid < 288) {                           // ---- quant ----
        int idx = (bid - 160) * 256 + tid;
        const float4* c4 = (const float4*)cont;
        float s = 0.f;
#pragma unroll
        for (int k = 0; k < 8; ++k) {
            float4 v = c4[idx + k * 32768];
            s += fabsf(fabsf(v.x) - 1.f) + fabsf(fabsf(v.y) - 1.f) +
                 fabsf(fabsf(v.z) - 1.f) + fabsf(fabsf(v.w) - 1.f);
        }
#pragma unroll
        for (int o = 32; o; o >>= 1) s += __shfl_down(s, o);
        __shared__ float sw[4];
        if (lane == 0) sw[wv] = s;
        __syncthreads();
        if (tid == 0) ws_f[QUANT_OFF + (bid - 160)] = sw[0] + sw[1] + sw[2] + sw[3];
    } else {                                          // ---- bit colsums ----
        int b = bid - 288;                            // 64 blocks x 128 rows
        int col = tid & 127, half = tid >> 7;
        long base = (long)b * 128;
        float s = 0.f;
        for (int r = half; r < 128; r += 2)
            s += bin[(base + r) * L_SZ + col];
        __shared__ float sh[256];
        sh[tid] = s;
        __syncthreads();
        if (tid < 128) ws_f[BITS_OFF + b * 128 + tid] = sh[tid] + sh[tid + 128];
    }
}

// ---- Kernel B: tiny finale — 32-count scan, cutoff rewalk, combine -------
__global__ __launch_bounds__(256) void k_fin(const void* __restrict__ wsv,
                                             float* __restrict__ out) {
    const float* ws_f = (const float*)wsv;
    const int* ws_i = (const int*)wsv;
    const int t = threadIdx.x, lane = t & 63, wv = t >> 6;
    __shared__ int meta[2];                           // cstar, rem
    __shared__ int wtot[4], woff_s[4];
    __shared__ float sh[256];
    __shared__ float fred[4];

    if (wv == 0) {                                    // scan 32 block counts (mask poison!)
        int c = (lane < NBLK_G) ? ws_i[CNT_OFF + lane] : 0;
        int x = c;
#pragma unroll
        for (int o = 1; o < 64; o <<= 1) {
            int y = __shfl_up(x, o);
            if (lane >= o) x += y;
        }
        if ((x - c) < P_PAIRS && x >= P_PAIRS) {      // unique crossing lane
            meta[0] = lane; meta[1] = P_PAIRS - (x - c);
        }
    }
    __syncthreads();
    const int cstar = meta[0], rem = meta[1];

    // rank within cutoff block via ballot scan over 256 entries
    unsigned long long cw =
        ((const unsigned long long*)(ws_i + CB_OFF))[cstar * 4 + wv];
    const bool cand = (cw >> lane) & 1ull;
    unsigned long long bm = __ballot(cand);
    int rw = __popcll(bm & ((1ull << lane) - 1ull));
    if (lane == 63) wtot[wv] = __popcll(bm);
    __syncthreads();
    if (t == 0) { int s = 0; for (int w = 0; w < 4; ++w) { woff_s[w] = s; s += wtot[w]; } }
    __syncthreads();
    const int rank = woff_s[wv] + rw;

    const float inv2p = 1.0f / (float)(2 * P_PAIRS);
    float val = 0.f;
    if (cand && rank < rem) {
        float g = ws_f[GRAM_OFF + cstar * 256 + t];
        float u = fmaxf(g + MARGIN, 0.f);
        val += u * u * inv2p;
    }
    if (t < NBLK_G && t < cstar) val += ws_f[VSUM_OFF + t] * inv2p;
    val += (ws_f[POS_OFF + t] + ws_f[POS_OFF + 256 + t]) * inv2p;
    if (t < 128) val += ws_f[QUANT_OFF + t] * (0.5f / (float)(B_SZ * L_SZ));

    {   // bit-balance: 64 partials per col
        int col = t & 127, g = t >> 7;
        float s2 = 0.f;
        for (int b = g * 32; b < g * 32 + 32; ++b) s2 += ws_f[BITS_OFF + b * 128 + col];
        sh[t] = s2;
    }
    __syncthreads();
    if (t < 128) {
        float cs = sh[t] + sh[t + 128];
        float m = cs * (1.0f / (float)B_SZ);
        val += 0.1f * m * m;
    }
    __syncthreads();
#pragma unroll
    for (int o = 32; o; o >>= 1) val += __shfl_down(val, o);
    if (lane == 0) fred[wv] = val;
    __syncthreads();
    if (t == 0) out[0] = fred[0] + fred[1] + fred[2] + fred[3];
}

extern "C" void kernel_launch(void* const* d_in, const int* in_sizes, int n_in,
                              void* d_out, int out_size, void* d_ws, size_t ws_size,
                              hipStream_t stream) {
    const float* bin = (const float*)d_in[0];
    const float* cont = (const float*)d_in[1];
    const int* pos = (const int*)d_in[2];
    float* out = (float*)d_out;

    k_all<<<352, 256, 0, stream>>>(bin, cont, pos, d_ws);
    k_fin<<<1, 256, 0, stream>>>(d_ws, out);
}